// Round 1
// baseline (1389.763 us; speedup 1.0000x reference)
//
#include <hip/hip_runtime.h>
#include <hip/hip_bf16.h>

typedef __attribute__((ext_vector_type(8))) __bf16 bf16x8;
typedef __attribute__((ext_vector_type(4))) float f32x4;

#define NN 100000
#define NE 1600000

// AX = (1+eps)*x   (written into d_out, which doubles as the AX buffer)
__global__ void init_ax_kernel(const float4* __restrict__ x, float4* __restrict__ AX,
                               const float* __restrict__ eps, int n4) {
    int i = blockIdx.x * blockDim.x + threadIdx.x;
    if (i >= n4) return;
    float s = 1.0f + eps[0];
    float4 v = x[i];
    v.x *= s; v.y *= s; v.z *= s; v.w *= s;
    AX[i] = v;
}

// Transpose + convert weights to bf16: W1T[n][k] (256x128), W2T[n][k] (128x256)
__global__ void convert_weights_kernel(const float* __restrict__ W1, const float* __restrict__ W2,
                                       __bf16* __restrict__ W1T, __bf16* __restrict__ W2T) {
    int tid = blockIdx.x * blockDim.x + threadIdx.x;   // 0..32767
    if (tid < 128 * 256) {
        int k1 = tid >> 8, n1 = tid & 255;             // W1 is [128][256]
        W1T[n1 * 128 + k1] = (__bf16)W1[tid];
        int k2 = tid >> 7, n2 = tid & 127;             // W2 is [256][128]
        W2T[n2 * 256 + k2] = (__bf16)W2[tid];
    }
}

// One wave per edge; 64 lanes x float2 = 128 floats. AX[dst] += val * x[src]
__global__ void scatter_kernel(const float2* __restrict__ x2, const float* __restrict__ ev,
                               const int* __restrict__ esrc, const int* __restrict__ edst,
                               float* AX) {
    unsigned gid = blockIdx.x * 256u + threadIdx.x;
    unsigned e = gid >> 6;
    unsigned lane = gid & 63u;
    if (e >= NE) return;
    float v = ev[e];
    int s = esrc[e], d = edst[e];
    float2 xv = x2[(size_t)s * 64 + lane];
    float* dstp = AX + (size_t)d * 128 + lane * 2;
    atomicAdd(dstp,     v * xv.x);
    atomicAdd(dstp + 1, v * xv.y);
}

// Fused 2-layer MLP: out = relu(AX@W1 + b1) @ W2 + b2
// Block: 256 threads (4 waves), BM=64 rows. In-place: AX and out may alias
// (all AX reads happen before __syncthreads(); all out writes after).
__global__ __launch_bounds__(256) void mlp_kernel(const float* AX,
                                                  const __bf16* __restrict__ W1T,
                                                  const __bf16* __restrict__ W2T,
                                                  const float* __restrict__ b1,
                                                  const float* __restrict__ b2,
                                                  float* out) {
    __shared__ __bf16 Hl[64][264];   // +8 bf16 pad -> row stride 528B, kills bank conflicts

    const int wave = threadIdx.x >> 6;
    const int lane = threadIdx.x & 63;
    const int l15  = lane & 15;
    const int lhi  = lane >> 4;
    const int rowbase = blockIdx.x * 64;

    // ---- Stage 1: H = relu(AX_tile @ W1 + b1), wave w owns 64 cols [w*64, w*64+64)
    f32x4 acc1[4][4] = {};
#pragma unroll
    for (int ks = 0; ks < 4; ++ks) {
        const int k0 = ks * 32 + lhi * 8;
        bf16x8 am[4], bn[4];
#pragma unroll
        for (int mt = 0; mt < 4; ++mt) {
            int row = rowbase + mt * 16 + l15;
            if (row >= NN) row = NN - 1;               // tail clamp (row stays in this block's range)
            const float4* ap = (const float4*)(AX + (size_t)row * 128 + k0);
            float4 f0 = ap[0], f1 = ap[1];
            bf16x8 a;
            a[0]=(__bf16)f0.x; a[1]=(__bf16)f0.y; a[2]=(__bf16)f0.z; a[3]=(__bf16)f0.w;
            a[4]=(__bf16)f1.x; a[5]=(__bf16)f1.y; a[6]=(__bf16)f1.z; a[7]=(__bf16)f1.w;
            am[mt] = a;
        }
#pragma unroll
        for (int nt = 0; nt < 4; ++nt) {
            int n = wave * 64 + nt * 16 + l15;
            bn[nt] = *(const bf16x8*)(W1T + (size_t)n * 128 + k0);
        }
#pragma unroll
        for (int mt = 0; mt < 4; ++mt)
#pragma unroll
            for (int nt = 0; nt < 4; ++nt)
                acc1[mt][nt] = __builtin_amdgcn_mfma_f32_16x16x32_bf16(am[mt], bn[nt], acc1[mt][nt], 0, 0, 0);
    }

    // epilogue 1: bias + relu + bf16 -> LDS
#pragma unroll
    for (int nt = 0; nt < 4; ++nt) {
        int n = wave * 64 + nt * 16 + l15;
        float bias = b1[n];
#pragma unroll
        for (int mt = 0; mt < 4; ++mt)
#pragma unroll
            for (int r = 0; r < 4; ++r) {
                float h = acc1[mt][nt][r] + bias;
                Hl[mt * 16 + lhi * 4 + r][n] = (__bf16)fmaxf(h, 0.0f);
            }
    }
    __syncthreads();

    // ---- Stage 2: OUT = H @ W2 + b2, wave w owns 32 cols [w*32, w*32+32)
    f32x4 acc2[4][2] = {};
#pragma unroll
    for (int ks = 0; ks < 8; ++ks) {
        const int k0 = ks * 32 + lhi * 8;
        bf16x8 ha[4], wb[2];
#pragma unroll
        for (int mt = 0; mt < 4; ++mt)
            ha[mt] = *(const bf16x8*)(&Hl[mt * 16 + l15][k0]);
#pragma unroll
        for (int nt = 0; nt < 2; ++nt) {
            int n = wave * 32 + nt * 16 + l15;
            wb[nt] = *(const bf16x8*)(W2T + (size_t)n * 256 + k0);
        }
#pragma unroll
        for (int mt = 0; mt < 4; ++mt)
#pragma unroll
            for (int nt = 0; nt < 2; ++nt)
                acc2[mt][nt] = __builtin_amdgcn_mfma_f32_16x16x32_bf16(ha[mt], wb[nt], acc2[mt][nt], 0, 0, 0);
    }

    // epilogue 2: + b2, store fp32
#pragma unroll
    for (int nt = 0; nt < 2; ++nt) {
        int n = wave * 32 + nt * 16 + l15;
        float bias = b2[n];
#pragma unroll
        for (int mt = 0; mt < 4; ++mt)
#pragma unroll
            for (int r = 0; r < 4; ++r) {
                int row = rowbase + mt * 16 + lhi * 4 + r;
                if (row < NN) out[(size_t)row * 128 + n] = acc2[mt][nt][r] + bias;
            }
    }
}

extern "C" void kernel_launch(void* const* d_in, const int* in_sizes, int n_in,
                              void* d_out, int out_size, void* d_ws, size_t ws_size,
                              hipStream_t stream) {
    const float* x    = (const float*)d_in[0];
    const float* ev   = (const float*)d_in[1];
    const float* W1   = (const float*)d_in[2];
    const float* b1   = (const float*)d_in[3];
    const float* W2   = (const float*)d_in[4];
    const float* b2   = (const float*)d_in[5];
    const float* eps  = (const float*)d_in[6];
    const int*   esrc = (const int*)d_in[7];
    const int*   edst = (const int*)d_in[8];
    float* out = (float*)d_out;

    __bf16* W1T = (__bf16*)d_ws;            // 256*128 bf16
    __bf16* W2T = W1T + 128 * 256;          // 128*256 bf16

    convert_weights_kernel<<<128, 256, 0, stream>>>(W1, W2, W1T, W2T);

    int n4 = NN * 128 / 4;
    init_ax_kernel<<<(n4 + 255) / 256, 256, 0, stream>>>((const float4*)x, (float4*)out, eps, n4);

    scatter_kernel<<<(NE * 64u) / 256u, 256, 0, stream>>>((const float2*)x, ev, esrc, edst, out);

    int nblk = (NN + 63) / 64;   // 1563
    mlp_kernel<<<nblk, 256, 0, stream>>>(out, W1T, W2T, b1, b2, out);
}

// Round 2
// 380.642 us; speedup vs baseline: 3.6511x; 3.6511x over previous
//
#include <hip/hip_runtime.h>
#include <hip/hip_bf16.h>

typedef __attribute__((ext_vector_type(8))) __bf16 bf16x8;
typedef __attribute__((ext_vector_type(4))) float f32x4;

#define NN 100000
#define NE 1600000
#define NB1 391          // ceil(NN/256)

// ---------------- weights: transpose + bf16 ----------------
__global__ void convert_weights_kernel(const float* __restrict__ W1, const float* __restrict__ W2,
                                       __bf16* __restrict__ W1T, __bf16* __restrict__ W2T) {
    int tid = blockIdx.x * blockDim.x + threadIdx.x;   // 0..32767
    if (tid < 128 * 256) {
        int k1 = tid >> 8, n1 = tid & 255;             // W1 is [128][256]
        W1T[n1 * 128 + k1] = (__bf16)W1[tid];
        int k2 = tid >> 7, n2 = tid & 127;             // W2 is [256][128]
        W2T[n2 * 256 + k2] = (__bf16)W2[tid];
    }
}

// ---------------- CSR build ----------------
__global__ void hist_kernel(const int* __restrict__ edst, int* __restrict__ cnt) {
    int stride = gridDim.x * blockDim.x;
    for (int e = blockIdx.x * blockDim.x + threadIdx.x; e < NE; e += stride)
        atomicAdd(&cnt[edst[e]], 1);
}

__global__ void scan_block_sums(const int* __restrict__ cnt, int* __restrict__ bsum) {
    __shared__ int sm[256];
    int i = blockIdx.x * 256 + threadIdx.x;
    sm[threadIdx.x] = (i < NN) ? cnt[i] : 0;
    __syncthreads();
    for (int s = 128; s > 0; s >>= 1) {
        if (threadIdx.x < s) sm[threadIdx.x] += sm[threadIdx.x + s];
        __syncthreads();
    }
    if (threadIdx.x == 0) bsum[blockIdx.x] = sm[0];
}

__global__ void scan_partials(const int* __restrict__ bsum, int* __restrict__ boff) {
    __shared__ int sm[512];
    int t = threadIdx.x;
    int v = (t < NB1) ? bsum[t] : 0;
    sm[t] = v; __syncthreads();
    for (int off = 1; off < 512; off <<= 1) {
        int add = (t >= off) ? sm[t - off] : 0;
        __syncthreads();
        sm[t] += add;
        __syncthreads();
    }
    if (t < NB1) boff[t] = sm[t] - v;   // exclusive
}

__global__ void scan_write_offsets(const int* __restrict__ cnt, const int* __restrict__ boff,
                                   int* __restrict__ node_off, int* __restrict__ cursor) {
    __shared__ int sm[256];
    int t = threadIdx.x;
    int i = blockIdx.x * 256 + t;
    int v = (i < NN) ? cnt[i] : 0;
    sm[t] = v; __syncthreads();
    for (int off = 1; off < 256; off <<= 1) {
        int add = (t >= off) ? sm[t - off] : 0;
        __syncthreads();
        sm[t] += add;
        __syncthreads();
    }
    int excl = sm[t] - v + boff[blockIdx.x];
    if (i < NN) { node_off[i] = excl; cursor[i] = excl; }
    if (i == 0) node_off[NN] = NE;
}

__global__ void reorder_kernel(const int* __restrict__ esrc, const int* __restrict__ edst,
                               const float* __restrict__ ev,
                               int* cursor, int* __restrict__ ssrc, float* __restrict__ sval) {
    int e = blockIdx.x * 256 + threadIdx.x;
    if (e >= NE) return;
    int d = edst[e];
    int pos = atomicAdd(&cursor[d], 1);
    ssrc[pos] = esrc[e];
    sval[pos] = ev[e];
}

// ---------------- per-node gather reduce: AX = (1+eps)*x + sum val*x[src] ----------------
__global__ __launch_bounds__(256) void gather_reduce_kernel(const float2* __restrict__ x2,
                                                            const int* __restrict__ node_off,
                                                            const int* __restrict__ ssrc,
                                                            const float* __restrict__ sval,
                                                            const float* __restrict__ eps,
                                                            float2* __restrict__ AX2) {
    unsigned gid = blockIdx.x * 256u + threadIdx.x;
    unsigned n = gid >> 6, lane = gid & 63u;
    if (n >= NN) return;
    int beg = node_off[n], end = node_off[n + 1];
    float2 xs = x2[(size_t)n * 64 + lane];
    float sc = 1.0f + eps[0];
    float2 acc; acc.x = sc * xs.x; acc.y = sc * xs.y;
    int j = beg;
    for (; j + 1 < end; j += 2) {
        int   sA = ssrc[j],  sB = ssrc[j + 1];
        float vA = sval[j],  vB = sval[j + 1];
        float2 xA = x2[(size_t)sA * 64 + lane];
        float2 xB = x2[(size_t)sB * 64 + lane];
        acc.x += vA * xA.x; acc.y += vA * xA.y;
        acc.x += vB * xB.x; acc.y += vB * xB.y;
    }
    if (j < end) {
        int s = ssrc[j]; float v = sval[j];
        float2 xA = x2[(size_t)s * 64 + lane];
        acc.x += v * xA.x; acc.y += v * xA.y;
    }
    AX2[(size_t)n * 64 + lane] = acc;
}

// ---------------- fallback path (atomic scatter), used only if ws too small ----------------
__global__ void init_ax_kernel(const float4* __restrict__ x, float4* __restrict__ AX,
                               const float* __restrict__ eps, int n4) {
    int i = blockIdx.x * blockDim.x + threadIdx.x;
    if (i >= n4) return;
    float s = 1.0f + eps[0];
    float4 v = x[i];
    v.x *= s; v.y *= s; v.z *= s; v.w *= s;
    AX[i] = v;
}

__global__ void scatter_kernel(const float2* __restrict__ x2, const float* __restrict__ ev,
                               const int* __restrict__ esrc, const int* __restrict__ edst,
                               float* AX) {
    unsigned gid = blockIdx.x * 256u + threadIdx.x;
    unsigned e = gid >> 6;
    unsigned lane = gid & 63u;
    if (e >= NE) return;
    float v = ev[e];
    int s = esrc[e], d = edst[e];
    float2 xv = x2[(size_t)s * 64 + lane];
    float* dstp = AX + (size_t)d * 128 + lane * 2;
    atomicAdd(dstp,     v * xv.x);
    atomicAdd(dstp + 1, v * xv.y);
}

// ---------------- fused 2-layer MLP: out = relu(AX@W1+b1)@W2+b2 ----------------
__global__ __launch_bounds__(256) void mlp_kernel(const float* AX,
                                                  const __bf16* __restrict__ W1T,
                                                  const __bf16* __restrict__ W2T,
                                                  const float* __restrict__ b1,
                                                  const float* __restrict__ b2,
                                                  float* out) {
    __shared__ __bf16 Hl[64][264];

    const int wave = threadIdx.x >> 6;
    const int lane = threadIdx.x & 63;
    const int l15  = lane & 15;
    const int lhi  = lane >> 4;
    const int rowbase = blockIdx.x * 64;

    f32x4 acc1[4][4] = {};
#pragma unroll
    for (int ks = 0; ks < 4; ++ks) {
        const int k0 = ks * 32 + lhi * 8;
        bf16x8 am[4], bn[4];
#pragma unroll
        for (int mt = 0; mt < 4; ++mt) {
            int row = rowbase + mt * 16 + l15;
            if (row >= NN) row = NN - 1;
            const float4* ap = (const float4*)(AX + (size_t)row * 128 + k0);
            float4 f0 = ap[0], f1 = ap[1];
            bf16x8 a;
            a[0]=(__bf16)f0.x; a[1]=(__bf16)f0.y; a[2]=(__bf16)f0.z; a[3]=(__bf16)f0.w;
            a[4]=(__bf16)f1.x; a[5]=(__bf16)f1.y; a[6]=(__bf16)f1.z; a[7]=(__bf16)f1.w;
            am[mt] = a;
        }
#pragma unroll
        for (int nt = 0; nt < 4; ++nt) {
            int n = wave * 64 + nt * 16 + l15;
            bn[nt] = *(const bf16x8*)(W1T + (size_t)n * 128 + k0);
        }
#pragma unroll
        for (int mt = 0; mt < 4; ++mt)
#pragma unroll
            for (int nt = 0; nt < 4; ++nt)
                acc1[mt][nt] = __builtin_amdgcn_mfma_f32_16x16x32_bf16(am[mt], bn[nt], acc1[mt][nt], 0, 0, 0);
    }

#pragma unroll
    for (int nt = 0; nt < 4; ++nt) {
        int n = wave * 64 + nt * 16 + l15;
        float bias = b1[n];
#pragma unroll
        for (int mt = 0; mt < 4; ++mt)
#pragma unroll
            for (int r = 0; r < 4; ++r) {
                float h = acc1[mt][nt][r] + bias;
                Hl[mt * 16 + lhi * 4 + r][n] = (__bf16)fmaxf(h, 0.0f);
            }
    }
    __syncthreads();

    f32x4 acc2[4][2] = {};
#pragma unroll
    for (int ks = 0; ks < 8; ++ks) {
        const int k0 = ks * 32 + lhi * 8;
        bf16x8 ha[4], wb[2];
#pragma unroll
        for (int mt = 0; mt < 4; ++mt)
            ha[mt] = *(const bf16x8*)(&Hl[mt * 16 + l15][k0]);
#pragma unroll
        for (int nt = 0; nt < 2; ++nt) {
            int n = wave * 32 + nt * 16 + l15;
            wb[nt] = *(const bf16x8*)(W2T + (size_t)n * 256 + k0);
        }
#pragma unroll
        for (int mt = 0; mt < 4; ++mt)
#pragma unroll
            for (int nt = 0; nt < 2; ++nt)
                acc2[mt][nt] = __builtin_amdgcn_mfma_f32_16x16x32_bf16(ha[mt], wb[nt], acc2[mt][nt], 0, 0, 0);
    }

#pragma unroll
    for (int nt = 0; nt < 2; ++nt) {
        int n = wave * 32 + nt * 16 + l15;
        float bias = b2[n];
#pragma unroll
        for (int mt = 0; mt < 4; ++mt)
#pragma unroll
            for (int r = 0; r < 4; ++r) {
                int row = rowbase + mt * 16 + lhi * 4 + r;
                if (row < NN) out[(size_t)row * 128 + n] = acc2[mt][nt][r] + bias;
            }
    }
}

extern "C" void kernel_launch(void* const* d_in, const int* in_sizes, int n_in,
                              void* d_out, int out_size, void* d_ws, size_t ws_size,
                              hipStream_t stream) {
    const float* x    = (const float*)d_in[0];
    const float* ev   = (const float*)d_in[1];
    const float* W1   = (const float*)d_in[2];
    const float* b1   = (const float*)d_in[3];
    const float* W2   = (const float*)d_in[4];
    const float* b2   = (const float*)d_in[5];
    const float* eps  = (const float*)d_in[6];
    const int*   esrc = (const int*)d_in[7];
    const int*   edst = (const int*)d_in[8];
    float* out = (float*)d_out;

    char* ws = (char*)d_ws;
    size_t off = 0;
    auto alloc = [&](size_t bytes) { void* p = ws + off; off += (bytes + 511) & ~size_t(511); return p; };

    __bf16* W1T   = (__bf16*)alloc(128 * 256 * sizeof(__bf16));
    __bf16* W2T   = (__bf16*)alloc(128 * 256 * sizeof(__bf16));
    int* cnt      = (int*)  alloc(NN * sizeof(int));
    int* node_off = (int*)  alloc((NN + 1) * sizeof(int));
    int* cursor   = (int*)  alloc((NN + 1) * sizeof(int));
    int* bsum     = (int*)  alloc(NB1 * sizeof(int));
    int* boff     = (int*)  alloc(NB1 * sizeof(int));
    int* ssrc     = (int*)  alloc(NE * sizeof(int));
    float* sval   = (float*)alloc(NE * sizeof(float));
    bool csr_ok = (off <= ws_size);

    convert_weights_kernel<<<128, 256, 0, stream>>>(W1, W2, W1T, W2T);

    if (csr_ok) {
        hipMemsetAsync(cnt, 0, NN * sizeof(int), stream);
        hist_kernel<<<1024, 256, 0, stream>>>(edst, cnt);
        scan_block_sums<<<NB1, 256, 0, stream>>>(cnt, bsum);
        scan_partials<<<1, 512, 0, stream>>>(bsum, boff);
        scan_write_offsets<<<NB1, 256, 0, stream>>>(cnt, boff, node_off, cursor);
        reorder_kernel<<<(NE + 255) / 256, 256, 0, stream>>>(esrc, edst, ev, cursor, ssrc, sval);
        gather_reduce_kernel<<<(NN * 64 + 255) / 256, 256, 0, stream>>>(
            (const float2*)x, node_off, ssrc, sval, eps, (float2*)out);
    } else {
        int n4 = NN * 128 / 4;
        init_ax_kernel<<<(n4 + 255) / 256, 256, 0, stream>>>((const float4*)x, (float4*)out, eps, n4);
        scatter_kernel<<<(NE * 64u) / 256u, 256, 0, stream>>>((const float2*)x, ev, esrc, edst, out);
    }

    int nblk = (NN + 63) / 64;
    mlp_kernel<<<nblk, 256, 0, stream>>>(out, W1T, W2T, b1, b2, out);
}

// Round 3
// 328.992 us; speedup vs baseline: 4.2243x; 1.1570x over previous
//
#include <hip/hip_runtime.h>
#include <hip/hip_bf16.h>
#include <type_traits>

typedef __attribute__((ext_vector_type(8))) __bf16 bf16x8;
typedef __attribute__((ext_vector_type(4))) float f32x4;

#define NN 100000
#define NE 1600000
#define NB1 391          // ceil(NN/256)

// ---------------- weights: transpose + bf16 ----------------
__global__ void convert_weights_kernel(const float* __restrict__ W1, const float* __restrict__ W2,
                                       __bf16* __restrict__ W1T, __bf16* __restrict__ W2T) {
    int tid = blockIdx.x * blockDim.x + threadIdx.x;   // 0..32767
    if (tid < 128 * 256) {
        int k1 = tid >> 8, n1 = tid & 255;             // W1 is [128][256]
        W1T[n1 * 128 + k1] = (__bf16)W1[tid];
        int k2 = tid >> 7, n2 = tid & 127;             // W2 is [256][128]
        W2T[n2 * 256 + k2] = (__bf16)W2[tid];
    }
}

// x (fp32) -> xb (bf16), 4 elems/thread
__global__ void convert_x_kernel(const float4* __restrict__ x4, uint2* __restrict__ xb, int n4) {
    int i = blockIdx.x * blockDim.x + threadIdx.x;
    if (i >= n4) return;
    float4 v = x4[i];
    __bf16 b0 = (__bf16)v.x, b1 = (__bf16)v.y, b2 = (__bf16)v.z, b3 = (__bf16)v.w;
    unsigned short s0 = *(unsigned short*)&b0, s1 = *(unsigned short*)&b1;
    unsigned short s2 = *(unsigned short*)&b2, s3 = *(unsigned short*)&b3;
    uint2 o;
    o.x = (unsigned)s0 | ((unsigned)s1 << 16);
    o.y = (unsigned)s2 | ((unsigned)s3 << 16);
    xb[i] = o;
}

// ---------------- CSR build ----------------
__global__ void hist_kernel(const int* __restrict__ edst, int* __restrict__ cnt) {
    int stride = gridDim.x * blockDim.x;
    for (int e = blockIdx.x * blockDim.x + threadIdx.x; e < NE; e += stride)
        atomicAdd(&cnt[edst[e]], 1);
}

__global__ void scan_block_sums(const int* __restrict__ cnt, int* __restrict__ bsum) {
    __shared__ int sm[256];
    int i = blockIdx.x * 256 + threadIdx.x;
    sm[threadIdx.x] = (i < NN) ? cnt[i] : 0;
    __syncthreads();
    for (int s = 128; s > 0; s >>= 1) {
        if (threadIdx.x < s) sm[threadIdx.x] += sm[threadIdx.x + s];
        __syncthreads();
    }
    if (threadIdx.x == 0) bsum[blockIdx.x] = sm[0];
}

__global__ void scan_partials(const int* __restrict__ bsum, int* __restrict__ boff) {
    __shared__ int sm[512];
    int t = threadIdx.x;
    int v = (t < NB1) ? bsum[t] : 0;
    sm[t] = v; __syncthreads();
    for (int off = 1; off < 512; off <<= 1) {
        int add = (t >= off) ? sm[t - off] : 0;
        __syncthreads();
        sm[t] += add;
        __syncthreads();
    }
    if (t < NB1) boff[t] = sm[t] - v;   // exclusive
}

__global__ void scan_write_offsets(const int* __restrict__ cnt, const int* __restrict__ boff,
                                   int* __restrict__ node_off, int* __restrict__ cursor) {
    __shared__ int sm[256];
    int t = threadIdx.x;
    int i = blockIdx.x * 256 + t;
    int v = (i < NN) ? cnt[i] : 0;
    sm[t] = v; __syncthreads();
    for (int off = 1; off < 256; off <<= 1) {
        int add = (t >= off) ? sm[t - off] : 0;
        __syncthreads();
        sm[t] += add;
        __syncthreads();
    }
    int excl = sm[t] - v + boff[blockIdx.x];
    if (i < NN) { node_off[i] = excl; cursor[i] = excl; }
    if (i == 0) node_off[NN] = NE;
}

// single 8B scatter per edge: pairs[pos] = {src, val_bits}
__global__ void reorder_kernel(const int* __restrict__ esrc, const int* __restrict__ edst,
                               const float* __restrict__ ev,
                               int* cursor, int2* __restrict__ pairs) {
    int e = blockIdx.x * 256 + threadIdx.x;
    if (e >= NE) return;
    int d = edst[e];
    int pos = atomicAdd(&cursor[d], 1);
    int2 p; p.x = esrc[e]; p.y = __float_as_int(ev[e]);
    pairs[pos] = p;
}

// ---------------- per-node gather reduce (bf16 x): AXb = bf16((1+eps)*x + sum val*x[src]) ----------------
__device__ __forceinline__ void fma_bf2(float2& acc, float v, unsigned w) {
    acc.x = fmaf(v, __uint_as_float(w << 16), acc.x);
    acc.y = fmaf(v, __uint_as_float(w & 0xffff0000u), acc.y);
}

__global__ __launch_bounds__(256) void gather_reduce_kernel(const unsigned* __restrict__ xb,
                                                            const int* __restrict__ node_off,
                                                            const int2* __restrict__ pairs,
                                                            const float* __restrict__ eps,
                                                            unsigned* __restrict__ AXb) {
    unsigned gid = blockIdx.x * 256u + threadIdx.x;
    unsigned n = gid >> 6, lane = gid & 63u;
    if (n >= NN) return;
    int beg = node_off[n], end = node_off[n + 1];
    float2 acc = {0.f, 0.f};
    fma_bf2(acc, 1.0f + eps[0], xb[(size_t)n * 64 + lane]);
    int j = beg;
    for (; j + 3 < end; j += 4) {
        int2 p0 = pairs[j], p1 = pairs[j + 1], p2 = pairs[j + 2], p3 = pairs[j + 3];
        unsigned w0 = xb[(size_t)p0.x * 64 + lane];
        unsigned w1 = xb[(size_t)p1.x * 64 + lane];
        unsigned w2 = xb[(size_t)p2.x * 64 + lane];
        unsigned w3 = xb[(size_t)p3.x * 64 + lane];
        fma_bf2(acc, __int_as_float(p0.y), w0);
        fma_bf2(acc, __int_as_float(p1.y), w1);
        fma_bf2(acc, __int_as_float(p2.y), w2);
        fma_bf2(acc, __int_as_float(p3.y), w3);
    }
    for (; j < end; ++j) {
        int2 p = pairs[j];
        fma_bf2(acc, __int_as_float(p.y), xb[(size_t)p.x * 64 + lane]);
    }
    __bf16 b0 = (__bf16)acc.x, b1 = (__bf16)acc.y;
    unsigned short s0 = *(unsigned short*)&b0, s1 = *(unsigned short*)&b1;
    AXb[(size_t)n * 64 + lane] = (unsigned)s0 | ((unsigned)s1 << 16);
}

// ---------------- fallback path (atomic scatter, fp32 AX in d_out) ----------------
__global__ void init_ax_kernel(const float4* __restrict__ x, float4* __restrict__ AX,
                               const float* __restrict__ eps, int n4) {
    int i = blockIdx.x * blockDim.x + threadIdx.x;
    if (i >= n4) return;
    float s = 1.0f + eps[0];
    float4 v = x[i];
    v.x *= s; v.y *= s; v.z *= s; v.w *= s;
    AX[i] = v;
}

__global__ void scatter_kernel(const float2* __restrict__ x2, const float* __restrict__ ev,
                               const int* __restrict__ esrc, const int* __restrict__ edst,
                               float* AX) {
    unsigned gid = blockIdx.x * 256u + threadIdx.x;
    unsigned e = gid >> 6;
    unsigned lane = gid & 63u;
    if (e >= NE) return;
    float v = ev[e];
    int s = esrc[e], d = edst[e];
    float2 xv = x2[(size_t)s * 64 + lane];
    float* dstp = AX + (size_t)d * 128 + lane * 2;
    atomicAdd(dstp,     v * xv.x);
    atomicAdd(dstp + 1, v * xv.y);
}

// ---------------- fused 2-layer MLP: out = relu(A@W1+b1)@W2+b2, A is bf16 or fp32 ----------------
template <typename AT>
__global__ __launch_bounds__(256) void mlp_kernel(const AT* A,
                                                  const __bf16* __restrict__ W1T,
                                                  const __bf16* __restrict__ W2T,
                                                  const float* __restrict__ b1,
                                                  const float* __restrict__ b2,
                                                  float* out) {
    __shared__ __bf16 Hl[64][264];

    const int wave = threadIdx.x >> 6;
    const int lane = threadIdx.x & 63;
    const int l15  = lane & 15;
    const int lhi  = lane >> 4;
    const int rowbase = blockIdx.x * 64;

    f32x4 acc1[4][4] = {};
#pragma unroll
    for (int ks = 0; ks < 4; ++ks) {
        const int k0 = ks * 32 + lhi * 8;
        bf16x8 am[4], bn[4];
#pragma unroll
        for (int mt = 0; mt < 4; ++mt) {
            int row = rowbase + mt * 16 + l15;
            if (row >= NN) row = NN - 1;
            if constexpr (std::is_same<AT, __bf16>::value) {
                am[mt] = *(const bf16x8*)(A + (size_t)row * 128 + k0);
            } else {
                const float4* ap = (const float4*)(A + (size_t)row * 128 + k0);
                float4 f0 = ap[0], f1 = ap[1];
                bf16x8 a;
                a[0]=(__bf16)f0.x; a[1]=(__bf16)f0.y; a[2]=(__bf16)f0.z; a[3]=(__bf16)f0.w;
                a[4]=(__bf16)f1.x; a[5]=(__bf16)f1.y; a[6]=(__bf16)f1.z; a[7]=(__bf16)f1.w;
                am[mt] = a;
            }
        }
#pragma unroll
        for (int nt = 0; nt < 4; ++nt) {
            int n = wave * 64 + nt * 16 + l15;
            bn[nt] = *(const bf16x8*)(W1T + (size_t)n * 128 + k0);
        }
#pragma unroll
        for (int mt = 0; mt < 4; ++mt)
#pragma unroll
            for (int nt = 0; nt < 4; ++nt)
                acc1[mt][nt] = __builtin_amdgcn_mfma_f32_16x16x32_bf16(am[mt], bn[nt], acc1[mt][nt], 0, 0, 0);
    }

#pragma unroll
    for (int nt = 0; nt < 4; ++nt) {
        int n = wave * 64 + nt * 16 + l15;
        float bias = b1[n];
#pragma unroll
        for (int mt = 0; mt < 4; ++mt)
#pragma unroll
            for (int r = 0; r < 4; ++r) {
                float h = acc1[mt][nt][r] + bias;
                Hl[mt * 16 + lhi * 4 + r][n] = (__bf16)fmaxf(h, 0.0f);
            }
    }
    __syncthreads();

    f32x4 acc2[4][2] = {};
#pragma unroll
    for (int ks = 0; ks < 8; ++ks) {
        const int k0 = ks * 32 + lhi * 8;
        bf16x8 ha[4], wb[2];
#pragma unroll
        for (int mt = 0; mt < 4; ++mt)
            ha[mt] = *(const bf16x8*)(&Hl[mt * 16 + l15][k0]);
#pragma unroll
        for (int nt = 0; nt < 2; ++nt) {
            int n = wave * 32 + nt * 16 + l15;
            wb[nt] = *(const bf16x8*)(W2T + (size_t)n * 256 + k0);
        }
#pragma unroll
        for (int mt = 0; mt < 4; ++mt)
#pragma unroll
            for (int nt = 0; nt < 2; ++nt)
                acc2[mt][nt] = __builtin_amdgcn_mfma_f32_16x16x32_bf16(ha[mt], wb[nt], acc2[mt][nt], 0, 0, 0);
    }

#pragma unroll
    for (int nt = 0; nt < 2; ++nt) {
        int n = wave * 32 + nt * 16 + l15;
        float bias = b2[n];
#pragma unroll
        for (int mt = 0; mt < 4; ++mt)
#pragma unroll
            for (int r = 0; r < 4; ++r) {
                int row = rowbase + mt * 16 + lhi * 4 + r;
                if (row < NN) out[(size_t)row * 128 + n] = acc2[mt][nt][r] + bias;
            }
    }
}

extern "C" void kernel_launch(void* const* d_in, const int* in_sizes, int n_in,
                              void* d_out, int out_size, void* d_ws, size_t ws_size,
                              hipStream_t stream) {
    const float* x    = (const float*)d_in[0];
    const float* ev   = (const float*)d_in[1];
    const float* W1   = (const float*)d_in[2];
    const float* b1   = (const float*)d_in[3];
    const float* W2   = (const float*)d_in[4];
    const float* b2   = (const float*)d_in[5];
    const float* eps  = (const float*)d_in[6];
    const int*   esrc = (const int*)d_in[7];
    const int*   edst = (const int*)d_in[8];
    float* out = (float*)d_out;

    char* ws = (char*)d_ws;
    size_t off = 0;
    auto alloc = [&](size_t bytes) { void* p = ws + off; off += (bytes + 511) & ~size_t(511); return p; };

    __bf16* W1T   = (__bf16*)alloc(128 * 256 * sizeof(__bf16));
    __bf16* W2T   = (__bf16*)alloc(128 * 256 * sizeof(__bf16));
    int* cnt      = (int*)  alloc(NN * sizeof(int));
    int* node_off = (int*)  alloc((NN + 1) * sizeof(int));
    int* cursor   = (int*)  alloc((NN + 1) * sizeof(int));
    int* bsum     = (int*)  alloc(NB1 * sizeof(int));
    int* boff     = (int*)  alloc(NB1 * sizeof(int));
    int2* pairs   = (int2*) alloc(NE * sizeof(int2));
    unsigned* xb  = (unsigned*)alloc((size_t)NN * 64 * sizeof(unsigned));   // bf16 x
    unsigned* AXb = (unsigned*)alloc((size_t)NN * 64 * sizeof(unsigned));   // bf16 AX
    bool csr_ok = (off <= ws_size);

    convert_weights_kernel<<<128, 256, 0, stream>>>(W1, W2, W1T, W2T);

    int nblk = (NN + 63) / 64;   // 1563
    if (csr_ok) {
        int n4 = NN * 128 / 4;
        convert_x_kernel<<<(n4 + 255) / 256, 256, 0, stream>>>((const float4*)x, (uint2*)xb, n4);
        hipMemsetAsync(cnt, 0, NN * sizeof(int), stream);
        hist_kernel<<<1024, 256, 0, stream>>>(edst, cnt);
        scan_block_sums<<<NB1, 256, 0, stream>>>(cnt, bsum);
        scan_partials<<<1, 512, 0, stream>>>(bsum, boff);
        scan_write_offsets<<<NB1, 256, 0, stream>>>(cnt, boff, node_off, cursor);
        reorder_kernel<<<(NE + 255) / 256, 256, 0, stream>>>(esrc, edst, ev, cursor, pairs);
        gather_reduce_kernel<<<(NN * 64 + 255) / 256, 256, 0, stream>>>(
            xb, node_off, pairs, eps, AXb);
        mlp_kernel<__bf16><<<nblk, 256, 0, stream>>>((const __bf16*)AXb, W1T, W2T, b1, b2, out);
    } else {
        int n4 = NN * 128 / 4;
        init_ax_kernel<<<(n4 + 255) / 256, 256, 0, stream>>>((const float4*)x, (float4*)out, eps, n4);
        scatter_kernel<<<(NE * 64u) / 256u, 256, 0, stream>>>((const float2*)x, ev, esrc, edst, out);
        mlp_kernel<float><<<nblk, 256, 0, stream>>>(out, W1T, W2T, b1, b2, out);
    }
}

// Round 4
// 294.484 us; speedup vs baseline: 4.7193x; 1.1172x over previous
//
#include <hip/hip_runtime.h>
#include <hip/hip_bf16.h>
#include <type_traits>

typedef __attribute__((ext_vector_type(8))) __bf16 bf16x8;
typedef __attribute__((ext_vector_type(4))) float f32x4;

#define NN 100000
#define NE 1600000
#define NB1 391          // ceil(NN/256)
#define XRNG 12500       // NN/8 nodes per XCD group

// ---------------- weights: transpose + bf16 ----------------
__global__ void convert_weights_kernel(const float* __restrict__ W1, const float* __restrict__ W2,
                                       __bf16* __restrict__ W1T, __bf16* __restrict__ W2T) {
    int tid = blockIdx.x * blockDim.x + threadIdx.x;   // 0..32767
    if (tid < 128 * 256) {
        int k1 = tid >> 8, n1 = tid & 255;             // W1 is [128][256]
        W1T[n1 * 128 + k1] = (__bf16)W1[tid];
        int k2 = tid >> 7, n2 = tid & 127;             // W2 is [256][128]
        W2T[n2 * 256 + k2] = (__bf16)W2[tid];
    }
}

// x (fp32) -> xb (bf16), 4 elems/thread
__global__ void convert_x_kernel(const float4* __restrict__ x4, uint2* __restrict__ xb, int n4) {
    int i = blockIdx.x * blockDim.x + threadIdx.x;
    if (i >= n4) return;
    float4 v = x4[i];
    __bf16 b0 = (__bf16)v.x, b1 = (__bf16)v.y, b2 = (__bf16)v.z, b3 = (__bf16)v.w;
    unsigned short s0 = *(unsigned short*)&b0, s1 = *(unsigned short*)&b1;
    unsigned short s2 = *(unsigned short*)&b2, s3 = *(unsigned short*)&b3;
    uint2 o;
    o.x = (unsigned)s0 | ((unsigned)s1 << 16);
    o.y = (unsigned)s2 | ((unsigned)s3 << 16);
    xb[i] = o;
}

// ---------------- CSR build (XCD-partitioned by dst range) ----------------
// group = blockIdx&7 round-robins onto XCDs; each group scans all edges but
// only touches counters/outputs for its own dst range -> all atomics and
// scatter lines stay XCD-local (no cross-L2 partial-line writebacks).
__global__ void hist_xcd_kernel(const int* __restrict__ edst, int* __restrict__ cnt) {
    int grp  = blockIdx.x & 7;
    int blk  = blockIdx.x >> 3;
    int nblk = gridDim.x >> 3;
    int lo = grp * XRNG, hi = lo + XRNG;
    for (int e = blk * 256 + threadIdx.x; e < NE; e += nblk * 256) {
        int d = edst[e];
        if (d >= lo && d < hi) atomicAdd(&cnt[d], 1);
    }
}

__global__ void scan_block_sums(const int* __restrict__ cnt, int* __restrict__ bsum) {
    __shared__ int sm[256];
    int i = blockIdx.x * 256 + threadIdx.x;
    sm[threadIdx.x] = (i < NN) ? cnt[i] : 0;
    __syncthreads();
    for (int s = 128; s > 0; s >>= 1) {
        if (threadIdx.x < s) sm[threadIdx.x] += sm[threadIdx.x + s];
        __syncthreads();
    }
    if (threadIdx.x == 0) bsum[blockIdx.x] = sm[0];
}

__global__ void scan_partials(const int* __restrict__ bsum, int* __restrict__ boff) {
    __shared__ int sm[512];
    int t = threadIdx.x;
    int v = (t < NB1) ? bsum[t] : 0;
    sm[t] = v; __syncthreads();
    for (int off = 1; off < 512; off <<= 1) {
        int add = (t >= off) ? sm[t - off] : 0;
        __syncthreads();
        sm[t] += add;
        __syncthreads();
    }
    if (t < NB1) boff[t] = sm[t] - v;   // exclusive
}

__global__ void scan_write_offsets(const int* __restrict__ cnt, const int* __restrict__ boff,
                                   int* __restrict__ node_off, int* __restrict__ cursor) {
    __shared__ int sm[256];
    int t = threadIdx.x;
    int i = blockIdx.x * 256 + t;
    int v = (i < NN) ? cnt[i] : 0;
    sm[t] = v; __syncthreads();
    for (int off = 1; off < 256; off <<= 1) {
        int add = (t >= off) ? sm[t - off] : 0;
        __syncthreads();
        sm[t] += add;
        __syncthreads();
    }
    int excl = sm[t] - v + boff[blockIdx.x];
    if (i < NN) { node_off[i] = excl; cursor[i] = excl; }
    if (i == 0) node_off[NN] = NE;
}

// XCD-partitioned scatter: pairs[pos] = {src, val_bits}, pos within own dst range
__global__ void reorder_xcd_kernel(const int* __restrict__ esrc, const int* __restrict__ edst,
                                   const float* __restrict__ ev,
                                   int* cursor, int2* __restrict__ pairs) {
    int grp  = blockIdx.x & 7;
    int blk  = blockIdx.x >> 3;
    int nblk = gridDim.x >> 3;
    int lo = grp * XRNG, hi = lo + XRNG;
    for (int e = blk * 256 + threadIdx.x; e < NE; e += nblk * 256) {
        int d = edst[e];
        int s = esrc[e];           // unconditional coalesced loads
        float v = ev[e];
        if (d >= lo && d < hi) {
            int pos = atomicAdd(&cursor[d], 1);
            int2 p; p.x = s; p.y = __float_as_int(v);
            pairs[pos] = p;
        }
    }
}

// ---------------- per-node gather reduce (bf16 x): AXb = bf16((1+eps)*x + sum val*x[src]) ----------------
__device__ __forceinline__ void fma_bf2(float2& acc, float v, unsigned w) {
    acc.x = fmaf(v, __uint_as_float(w << 16), acc.x);
    acc.y = fmaf(v, __uint_as_float(w & 0xffff0000u), acc.y);
}

__global__ __launch_bounds__(256) void gather_reduce_kernel(const unsigned* __restrict__ xb,
                                                            const int* __restrict__ node_off,
                                                            const int2* __restrict__ pairs,
                                                            const float* __restrict__ eps,
                                                            unsigned* __restrict__ AXb) {
    unsigned gid = blockIdx.x * 256u + threadIdx.x;
    unsigned n = gid >> 6, lane = gid & 63u;
    if (n >= NN) return;
    int beg = node_off[n], end = node_off[n + 1];
    float2 acc = {0.f, 0.f};
    fma_bf2(acc, 1.0f + eps[0], xb[(size_t)n * 64 + lane]);
    int j = beg;
    for (; j + 3 < end; j += 4) {
        int2 p0 = pairs[j], p1 = pairs[j + 1], p2 = pairs[j + 2], p3 = pairs[j + 3];
        unsigned w0 = xb[(size_t)p0.x * 64 + lane];
        unsigned w1 = xb[(size_t)p1.x * 64 + lane];
        unsigned w2 = xb[(size_t)p2.x * 64 + lane];
        unsigned w3 = xb[(size_t)p3.x * 64 + lane];
        fma_bf2(acc, __int_as_float(p0.y), w0);
        fma_bf2(acc, __int_as_float(p1.y), w1);
        fma_bf2(acc, __int_as_float(p2.y), w2);
        fma_bf2(acc, __int_as_float(p3.y), w3);
    }
    for (; j < end; ++j) {
        int2 p = pairs[j];
        fma_bf2(acc, __int_as_float(p.y), xb[(size_t)p.x * 64 + lane]);
    }
    __bf16 b0 = (__bf16)acc.x, b1 = (__bf16)acc.y;
    unsigned short s0 = *(unsigned short*)&b0, s1 = *(unsigned short*)&b1;
    AXb[(size_t)n * 64 + lane] = (unsigned)s0 | ((unsigned)s1 << 16);
}

// ---------------- fallback path (atomic scatter, fp32 AX in d_out) ----------------
__global__ void init_ax_kernel(const float4* __restrict__ x, float4* __restrict__ AX,
                               const float* __restrict__ eps, int n4) {
    int i = blockIdx.x * blockDim.x + threadIdx.x;
    if (i >= n4) return;
    float s = 1.0f + eps[0];
    float4 v = x[i];
    v.x *= s; v.y *= s; v.z *= s; v.w *= s;
    AX[i] = v;
}

__global__ void scatter_kernel(const float2* __restrict__ x2, const float* __restrict__ ev,
                               const int* __restrict__ esrc, const int* __restrict__ edst,
                               float* AX) {
    unsigned gid = blockIdx.x * 256u + threadIdx.x;
    unsigned e = gid >> 6;
    unsigned lane = gid & 63u;
    if (e >= NE) return;
    float v = ev[e];
    int s = esrc[e], d = edst[e];
    float2 xv = x2[(size_t)s * 64 + lane];
    float* dstp = AX + (size_t)d * 128 + lane * 2;
    atomicAdd(dstp,     v * xv.x);
    atomicAdd(dstp + 1, v * xv.y);
}

// ---------------- fused 2-layer MLP: out = relu(A@W1+b1)@W2+b2, A is bf16 or fp32 ----------------
template <typename AT>
__global__ __launch_bounds__(256) void mlp_kernel(const AT* A,
                                                  const __bf16* __restrict__ W1T,
                                                  const __bf16* __restrict__ W2T,
                                                  const float* __restrict__ b1,
                                                  const float* __restrict__ b2,
                                                  float* out) {
    __shared__ __bf16 Hl[64][264];

    const int wave = threadIdx.x >> 6;
    const int lane = threadIdx.x & 63;
    const int l15  = lane & 15;
    const int lhi  = lane >> 4;
    const int rowbase = blockIdx.x * 64;

    f32x4 acc1[4][4] = {};
#pragma unroll
    for (int ks = 0; ks < 4; ++ks) {
        const int k0 = ks * 32 + lhi * 8;
        bf16x8 am[4], bn[4];
#pragma unroll
        for (int mt = 0; mt < 4; ++mt) {
            int row = rowbase + mt * 16 + l15;
            if (row >= NN) row = NN - 1;
            if constexpr (std::is_same<AT, __bf16>::value) {
                am[mt] = *(const bf16x8*)(A + (size_t)row * 128 + k0);
            } else {
                const float4* ap = (const float4*)(A + (size_t)row * 128 + k0);
                float4 f0 = ap[0], f1 = ap[1];
                bf16x8 a;
                a[0]=(__bf16)f0.x; a[1]=(__bf16)f0.y; a[2]=(__bf16)f0.z; a[3]=(__bf16)f0.w;
                a[4]=(__bf16)f1.x; a[5]=(__bf16)f1.y; a[6]=(__bf16)f1.z; a[7]=(__bf16)f1.w;
                am[mt] = a;
            }
        }
#pragma unroll
        for (int nt = 0; nt < 4; ++nt) {
            int n = wave * 64 + nt * 16 + l15;
            bn[nt] = *(const bf16x8*)(W1T + (size_t)n * 128 + k0);
        }
#pragma unroll
        for (int mt = 0; mt < 4; ++mt)
#pragma unroll
            for (int nt = 0; nt < 4; ++nt)
                acc1[mt][nt] = __builtin_amdgcn_mfma_f32_16x16x32_bf16(am[mt], bn[nt], acc1[mt][nt], 0, 0, 0);
    }

#pragma unroll
    for (int nt = 0; nt < 4; ++nt) {
        int n = wave * 64 + nt * 16 + l15;
        float bias = b1[n];
#pragma unroll
        for (int mt = 0; mt < 4; ++mt)
#pragma unroll
            for (int r = 0; r < 4; ++r) {
                float h = acc1[mt][nt][r] + bias;
                Hl[mt * 16 + lhi * 4 + r][n] = (__bf16)fmaxf(h, 0.0f);
            }
    }
    __syncthreads();

    f32x4 acc2[4][2] = {};
#pragma unroll
    for (int ks = 0; ks < 8; ++ks) {
        const int k0 = ks * 32 + lhi * 8;
        bf16x8 ha[4], wb[2];
#pragma unroll
        for (int mt = 0; mt < 4; ++mt)
            ha[mt] = *(const bf16x8*)(&Hl[mt * 16 + l15][k0]);
#pragma unroll
        for (int nt = 0; nt < 2; ++nt) {
            int n = wave * 32 + nt * 16 + l15;
            wb[nt] = *(const bf16x8*)(W2T + (size_t)n * 256 + k0);
        }
#pragma unroll
        for (int mt = 0; mt < 4; ++mt)
#pragma unroll
            for (int nt = 0; nt < 2; ++nt)
                acc2[mt][nt] = __builtin_amdgcn_mfma_f32_16x16x32_bf16(ha[mt], wb[nt], acc2[mt][nt], 0, 0, 0);
    }

#pragma unroll
    for (int nt = 0; nt < 2; ++nt) {
        int n = wave * 32 + nt * 16 + l15;
        float bias = b2[n];
#pragma unroll
        for (int mt = 0; mt < 4; ++mt)
#pragma unroll
            for (int r = 0; r < 4; ++r) {
                int row = rowbase + mt * 16 + lhi * 4 + r;
                if (row < NN) out[(size_t)row * 128 + n] = acc2[mt][nt][r] + bias;
            }
    }
}

extern "C" void kernel_launch(void* const* d_in, const int* in_sizes, int n_in,
                              void* d_out, int out_size, void* d_ws, size_t ws_size,
                              hipStream_t stream) {
    const float* x    = (const float*)d_in[0];
    const float* ev   = (const float*)d_in[1];
    const float* W1   = (const float*)d_in[2];
    const float* b1   = (const float*)d_in[3];
    const float* W2   = (const float*)d_in[4];
    const float* b2   = (const float*)d_in[5];
    const float* eps  = (const float*)d_in[6];
    const int*   esrc = (const int*)d_in[7];
    const int*   edst = (const int*)d_in[8];
    float* out = (float*)d_out;

    char* ws = (char*)d_ws;
    size_t off = 0;
    auto alloc = [&](size_t bytes) { void* p = ws + off; off += (bytes + 511) & ~size_t(511); return p; };

    __bf16* W1T   = (__bf16*)alloc(128 * 256 * sizeof(__bf16));
    __bf16* W2T   = (__bf16*)alloc(128 * 256 * sizeof(__bf16));
    int* cnt      = (int*)  alloc(NN * sizeof(int));
    int* node_off = (int*)  alloc((NN + 1) * sizeof(int));
    int* cursor   = (int*)  alloc((NN + 1) * sizeof(int));
    int* bsum     = (int*)  alloc(NB1 * sizeof(int));
    int* boff     = (int*)  alloc(NB1 * sizeof(int));
    int2* pairs   = (int2*) alloc(NE * sizeof(int2));
    unsigned* xb  = (unsigned*)alloc((size_t)NN * 64 * sizeof(unsigned));   // bf16 x
    unsigned* AXb = (unsigned*)alloc((size_t)NN * 64 * sizeof(unsigned));   // bf16 AX
    bool csr_ok = (off <= ws_size);

    convert_weights_kernel<<<128, 256, 0, stream>>>(W1, W2, W1T, W2T);

    int nblk = (NN + 63) / 64;   // 1563
    if (csr_ok) {
        int n4 = NN * 128 / 4;
        convert_x_kernel<<<(n4 + 255) / 256, 256, 0, stream>>>((const float4*)x, (uint2*)xb, n4);
        hipMemsetAsync(cnt, 0, NN * sizeof(int), stream);
        hist_xcd_kernel<<<2048, 256, 0, stream>>>(edst, cnt);
        scan_block_sums<<<NB1, 256, 0, stream>>>(cnt, bsum);
        scan_partials<<<1, 512, 0, stream>>>(bsum, boff);
        scan_write_offsets<<<NB1, 256, 0, stream>>>(cnt, boff, node_off, cursor);
        reorder_xcd_kernel<<<2048, 256, 0, stream>>>(esrc, edst, ev, cursor, pairs);
        gather_reduce_kernel<<<(NN * 64 + 255) / 256, 256, 0, stream>>>(
            xb, node_off, pairs, eps, AXb);
        mlp_kernel<__bf16><<<nblk, 256, 0, stream>>>((const __bf16*)AXb, W1T, W2T, b1, b2, out);
    } else {
        int n4 = NN * 128 / 4;
        init_ax_kernel<<<(n4 + 255) / 256, 256, 0, stream>>>((const float4*)x, (float4*)out, eps, n4);
        scatter_kernel<<<(NE * 64u) / 256u, 256, 0, stream>>>((const float2*)x, ev, esrc, edst, out);
        mlp_kernel<float><<<nblk, 256, 0, stream>>>(out, W1T, W2T, b1, b2, out);
    }
}

// Round 5
// 284.645 us; speedup vs baseline: 4.8824x; 1.0346x over previous
//
#include <hip/hip_runtime.h>
#include <hip/hip_bf16.h>
#include <type_traits>

typedef __attribute__((ext_vector_type(8))) __bf16 bf16x8;
typedef __attribute__((ext_vector_type(4))) float f32x4;

#define NN 100000
#define NE 1600000
#define NB1 391          // ceil(NN/256)
#define XRNG 12500       // NN/8 nodes per XCD group (reorder dst ranges)
#define ECHUNK 200000    // NE/8 edges per group (hist chunks)

// ---------------- converts: weights (transpose+bf16) and x (bf16), one kernel ----------------
__global__ void convert_kernel(const float* __restrict__ W1, const float* __restrict__ W2,
                               __bf16* __restrict__ W1T, __bf16* __restrict__ W2T,
                               const float4* __restrict__ x4, uint2* __restrict__ xb) {
    int tid = blockIdx.x * 256 + threadIdx.x;
    if (tid < 128 * 256) {
        int k1 = tid >> 8, n1 = tid & 255;             // W1 is [128][256]
        W1T[n1 * 128 + k1] = (__bf16)W1[tid];
        int k2 = tid >> 7, n2 = tid & 127;             // W2 is [256][128]
        W2T[n2 * 256 + k2] = (__bf16)W2[tid];
    } else {
        int i = tid - 128 * 256;
        if (i < NN * 32) {                             // n4 = NN*128/4
            float4 v = x4[i];
            __bf16 b0 = (__bf16)v.x, b1 = (__bf16)v.y, b2 = (__bf16)v.z, b3 = (__bf16)v.w;
            uint2 o;
            o.x = (unsigned)*(unsigned short*)&b0 | ((unsigned)*(unsigned short*)&b1 << 16);
            o.y = (unsigned)*(unsigned short*)&b2 | ((unsigned)*(unsigned short*)&b3 << 16);
            xb[i] = o;
        }
    }
}

// ---------------- CSR build ----------------
// Single-pass hist: group g = blockIdx&7 (lands on XCD g) scans edge chunk g,
// counting into its PRIVATE cnt8[g*NN..] -> atomics XCD-local, lines unshared.
__global__ void hist_kernel8(const int* __restrict__ edst, int* __restrict__ cnt8) {
    int grp  = blockIdx.x & 7;
    int blk  = blockIdx.x >> 3;
    int nblk = gridDim.x >> 3;
    int* mycnt = cnt8 + grp * NN;
    int lo = grp * ECHUNK, hi = lo + ECHUNK;
    if (hi > NE) hi = NE;
    for (int e = lo + blk * 256 + threadIdx.x; e < hi; e += nblk * 256)
        atomicAdd(&mycnt[edst[e]], 1);
}

__global__ void scan_block_sums(const int* __restrict__ cnt8, int* __restrict__ bsum) {
    __shared__ int sm[256];
    int i = blockIdx.x * 256 + threadIdx.x;
    int v = 0;
    if (i < NN) {
#pragma unroll
        for (int g = 0; g < 8; ++g) v += cnt8[g * NN + i];
    }
    sm[threadIdx.x] = v;
    __syncthreads();
    for (int s = 128; s > 0; s >>= 1) {
        if (threadIdx.x < s) sm[threadIdx.x] += sm[threadIdx.x + s];
        __syncthreads();
    }
    if (threadIdx.x == 0) bsum[blockIdx.x] = sm[0];
}

__global__ void scan_partials(const int* __restrict__ bsum, int* __restrict__ boff) {
    __shared__ int sm[512];
    int t = threadIdx.x;
    int v = (t < NB1) ? bsum[t] : 0;
    sm[t] = v; __syncthreads();
    for (int off = 1; off < 512; off <<= 1) {
        int add = (t >= off) ? sm[t - off] : 0;
        __syncthreads();
        sm[t] += add;
        __syncthreads();
    }
    if (t < NB1) boff[t] = sm[t] - v;   // exclusive
}

__global__ void scan_write_offsets(const int* __restrict__ cnt8, const int* __restrict__ boff,
                                   int* __restrict__ node_off, int* __restrict__ cursor) {
    __shared__ int sm[256];
    int t = threadIdx.x;
    int i = blockIdx.x * 256 + t;
    int v = 0;
    if (i < NN) {
#pragma unroll
        for (int g = 0; g < 8; ++g) v += cnt8[g * NN + i];
    }
    sm[t] = v; __syncthreads();
    for (int off = 1; off < 256; off <<= 1) {
        int add = (t >= off) ? sm[t - off] : 0;
        __syncthreads();
        sm[t] += add;
        __syncthreads();
    }
    int excl = sm[t] - v + boff[blockIdx.x];
    if (i < NN) { node_off[i] = excl; cursor[i] = excl; }
    if (i == 0) node_off[NN] = NE;
}

// XCD-partitioned scatter: pairs[pos] = {src_byte_offset, val_bits}
__global__ void reorder_xcd_kernel(const int* __restrict__ esrc, const int* __restrict__ edst,
                                   const float* __restrict__ ev,
                                   int* cursor, int2* __restrict__ pairs) {
    int grp  = blockIdx.x & 7;
    int blk  = blockIdx.x >> 3;
    int nblk = gridDim.x >> 3;
    int lo = grp * XRNG, hi = lo + XRNG;
    for (int e = blk * 256 + threadIdx.x; e < NE; e += nblk * 256) {
        int d = edst[e];
        int s = esrc[e];           // unconditional coalesced loads
        float v = ev[e];
        if (d >= lo && d < hi) {
            int pos = atomicAdd(&cursor[d], 1);
            int2 p; p.x = s << 8;  // pre-scaled: byte offset of row in xb (256B rows)
            p.y = __float_as_int(v);
            pairs[pos] = p;
        }
    }
}

// ---------------- per-node gather reduce (bf16 x, 2 edges/wave) ----------------
// Half-wave 0 (lanes 0-31) accumulates even edges, half-wave 1 odd edges;
// each half reads the full 256B row via uint2/lane. Combine via shfl_xor(32).
__device__ __forceinline__ float bflo(unsigned w) { return __uint_as_float(w << 16); }
__device__ __forceinline__ float bfhi(unsigned w) { return __uint_as_float(w & 0xffff0000u); }

__global__ __launch_bounds__(256) void gather_reduce_kernel(const unsigned* __restrict__ xb,
                                                            const int* __restrict__ node_off,
                                                            const int2* __restrict__ pairs,
                                                            const float* __restrict__ eps,
                                                            uint2* __restrict__ AXb) {
    unsigned gid = blockIdx.x * 256u + threadIdx.x;
    unsigned n = gid >> 6, lane = gid & 63u;
    if (n >= NN) return;
    const unsigned hw = lane >> 5, l32 = lane & 31u;
    const int beg = node_off[n], end = node_off[n + 1];
    const char* xbase = (const char*)xb + l32 * 8;   // this lane's 8B slot within any row
    float a0 = 0.f, a1 = 0.f, a2 = 0.f, a3 = 0.f;
    int j = beg + (int)hw;
    for (; j + 2 < end; j += 4) {                    // 2 edges per half per iter
        int2 pA = pairs[j], pB = pairs[j + 2];
        uint2 wA = *(const uint2*)(xbase + pA.x);
        uint2 wB = *(const uint2*)(xbase + pB.x);
        float vA = __int_as_float(pA.y), vB = __int_as_float(pB.y);
        a0 = fmaf(vA, bflo(wA.x), a0); a1 = fmaf(vA, bfhi(wA.x), a1);
        a2 = fmaf(vA, bflo(wA.y), a2); a3 = fmaf(vA, bfhi(wA.y), a3);
        a0 = fmaf(vB, bflo(wB.x), a0); a1 = fmaf(vB, bfhi(wB.x), a1);
        a2 = fmaf(vB, bflo(wB.y), a2); a3 = fmaf(vB, bfhi(wB.y), a3);
    }
    if (j < end) {
        int2 p = pairs[j];
        uint2 w = *(const uint2*)(xbase + p.x);
        float v = __int_as_float(p.y);
        a0 = fmaf(v, bflo(w.x), a0); a1 = fmaf(v, bfhi(w.x), a1);
        a2 = fmaf(v, bflo(w.y), a2); a3 = fmaf(v, bfhi(w.y), a3);
    }
    // combine the two half-wave partials
    a0 += __shfl_xor(a0, 32); a1 += __shfl_xor(a1, 32);
    a2 += __shfl_xor(a2, 32); a3 += __shfl_xor(a3, 32);
    if (hw == 0) {
        uint2 ws = *(const uint2*)(xbase + (size_t)n * 256);
        float sc = 1.0f + eps[0];
        a0 = fmaf(sc, bflo(ws.x), a0); a1 = fmaf(sc, bfhi(ws.x), a1);
        a2 = fmaf(sc, bflo(ws.y), a2); a3 = fmaf(sc, bfhi(ws.y), a3);
        __bf16 b0 = (__bf16)a0, b1 = (__bf16)a1, b2 = (__bf16)a2, b3 = (__bf16)a3;
        uint2 o;
        o.x = (unsigned)*(unsigned short*)&b0 | ((unsigned)*(unsigned short*)&b1 << 16);
        o.y = (unsigned)*(unsigned short*)&b2 | ((unsigned)*(unsigned short*)&b3 << 16);
        AXb[(size_t)n * 32 + l32] = o;
    }
}

// ---------------- fallback path (atomic scatter, fp32 AX in d_out) ----------------
__global__ void init_ax_kernel(const float4* __restrict__ x, float4* __restrict__ AX,
                               const float* __restrict__ eps, int n4) {
    int i = blockIdx.x * blockDim.x + threadIdx.x;
    if (i >= n4) return;
    float s = 1.0f + eps[0];
    float4 v = x[i];
    v.x *= s; v.y *= s; v.z *= s; v.w *= s;
    AX[i] = v;
}

__global__ void scatter_kernel(const float2* __restrict__ x2, const float* __restrict__ ev,
                               const int* __restrict__ esrc, const int* __restrict__ edst,
                               float* AX) {
    unsigned gid = blockIdx.x * 256u + threadIdx.x;
    unsigned e = gid >> 6;
    unsigned lane = gid & 63u;
    if (e >= NE) return;
    float v = ev[e];
    int s = esrc[e], d = edst[e];
    float2 xv = x2[(size_t)s * 64 + lane];
    float* dstp = AX + (size_t)d * 128 + lane * 2;
    atomicAdd(dstp,     v * xv.x);
    atomicAdd(dstp + 1, v * xv.y);
}

// ---------------- fused 2-layer MLP: out = relu(A@W1+b1)@W2+b2, A is bf16 or fp32 ----------------
template <typename AT>
__global__ __launch_bounds__(256) void mlp_kernel(const AT* A,
                                                  const __bf16* __restrict__ W1T,
                                                  const __bf16* __restrict__ W2T,
                                                  const float* __restrict__ b1,
                                                  const float* __restrict__ b2,
                                                  float* out) {
    __shared__ __bf16 Hl[64][264];

    const int wave = threadIdx.x >> 6;
    const int lane = threadIdx.x & 63;
    const int l15  = lane & 15;
    const int lhi  = lane >> 4;
    const int rowbase = blockIdx.x * 64;

    f32x4 acc1[4][4] = {};
#pragma unroll
    for (int ks = 0; ks < 4; ++ks) {
        const int k0 = ks * 32 + lhi * 8;
        bf16x8 am[4], bn[4];
#pragma unroll
        for (int mt = 0; mt < 4; ++mt) {
            int row = rowbase + mt * 16 + l15;
            if (row >= NN) row = NN - 1;
            if constexpr (std::is_same<AT, __bf16>::value) {
                am[mt] = *(const bf16x8*)(A + (size_t)row * 128 + k0);
            } else {
                const float4* ap = (const float4*)(A + (size_t)row * 128 + k0);
                float4 f0 = ap[0], f1 = ap[1];
                bf16x8 a;
                a[0]=(__bf16)f0.x; a[1]=(__bf16)f0.y; a[2]=(__bf16)f0.z; a[3]=(__bf16)f0.w;
                a[4]=(__bf16)f1.x; a[5]=(__bf16)f1.y; a[6]=(__bf16)f1.z; a[7]=(__bf16)f1.w;
                am[mt] = a;
            }
        }
#pragma unroll
        for (int nt = 0; nt < 4; ++nt) {
            int n = wave * 64 + nt * 16 + l15;
            bn[nt] = *(const bf16x8*)(W1T + (size_t)n * 128 + k0);
        }
#pragma unroll
        for (int mt = 0; mt < 4; ++mt)
#pragma unroll
            for (int nt = 0; nt < 4; ++nt)
                acc1[mt][nt] = __builtin_amdgcn_mfma_f32_16x16x32_bf16(am[mt], bn[nt], acc1[mt][nt], 0, 0, 0);
    }

#pragma unroll
    for (int nt = 0; nt < 4; ++nt) {
        int n = wave * 64 + nt * 16 + l15;
        float bias = b1[n];
#pragma unroll
        for (int mt = 0; mt < 4; ++mt)
#pragma unroll
            for (int r = 0; r < 4; ++r) {
                float h = acc1[mt][nt][r] + bias;
                Hl[mt * 16 + lhi * 4 + r][n] = (__bf16)fmaxf(h, 0.0f);
            }
    }
    __syncthreads();

    f32x4 acc2[4][2] = {};
#pragma unroll
    for (int ks = 0; ks < 8; ++ks) {
        const int k0 = ks * 32 + lhi * 8;
        bf16x8 ha[4], wb[2];
#pragma unroll
        for (int mt = 0; mt < 4; ++mt)
            ha[mt] = *(const bf16x8*)(&Hl[mt * 16 + l15][k0]);
#pragma unroll
        for (int nt = 0; nt < 2; ++nt) {
            int n = wave * 32 + nt * 16 + l15;
            wb[nt] = *(const bf16x8*)(W2T + (size_t)n * 256 + k0);
        }
#pragma unroll
        for (int mt = 0; mt < 4; ++mt)
#pragma unroll
            for (int nt = 0; nt < 2; ++nt)
                acc2[mt][nt] = __builtin_amdgcn_mfma_f32_16x16x32_bf16(ha[mt], wb[nt], acc2[mt][nt], 0, 0, 0);
    }

#pragma unroll
    for (int nt = 0; nt < 2; ++nt) {
        int n = wave * 32 + nt * 16 + l15;
        float bias = b2[n];
#pragma unroll
        for (int mt = 0; mt < 4; ++mt)
#pragma unroll
            for (int r = 0; r < 4; ++r) {
                int row = rowbase + mt * 16 + lhi * 4 + r;
                if (row < NN) out[(size_t)row * 128 + n] = acc2[mt][nt][r] + bias;
            }
    }
}

extern "C" void kernel_launch(void* const* d_in, const int* in_sizes, int n_in,
                              void* d_out, int out_size, void* d_ws, size_t ws_size,
                              hipStream_t stream) {
    const float* x    = (const float*)d_in[0];
    const float* ev   = (const float*)d_in[1];
    const float* W1   = (const float*)d_in[2];
    const float* b1   = (const float*)d_in[3];
    const float* W2   = (const float*)d_in[4];
    const float* b2   = (const float*)d_in[5];
    const float* eps  = (const float*)d_in[6];
    const int*   esrc = (const int*)d_in[7];
    const int*   edst = (const int*)d_in[8];
    float* out = (float*)d_out;

    char* ws = (char*)d_ws;
    size_t off = 0;
    auto alloc = [&](size_t bytes) { void* p = ws + off; off += (bytes + 511) & ~size_t(511); return p; };

    __bf16* W1T   = (__bf16*)alloc(128 * 256 * sizeof(__bf16));
    __bf16* W2T   = (__bf16*)alloc(128 * 256 * sizeof(__bf16));
    int* cnt8     = (int*)  alloc((size_t)NN * 8 * sizeof(int));
    int* node_off = (int*)  alloc((NN + 1) * sizeof(int));
    int* cursor   = (int*)  alloc((NN + 1) * sizeof(int));
    int* bsum     = (int*)  alloc(NB1 * sizeof(int));
    int* boff     = (int*)  alloc(NB1 * sizeof(int));
    int2* pairs   = (int2*) alloc(NE * sizeof(int2));
    unsigned* xb  = (unsigned*)alloc((size_t)NN * 64 * sizeof(unsigned));   // bf16 x
    unsigned* AXb = (unsigned*)alloc((size_t)NN * 64 * sizeof(unsigned));   // bf16 AX
    bool csr_ok = (off <= ws_size);

    int nblk = (NN + 63) / 64;   // 1563
    if (csr_ok) {
        int cblocks = 128 + (NN * 32 + 255) / 256;   // weights + x converts
        convert_kernel<<<cblocks, 256, 0, stream>>>(W1, W2, W1T, W2T, (const float4*)x, (uint2*)xb);
        hipMemsetAsync(cnt8, 0, (size_t)NN * 8 * sizeof(int), stream);
        hist_kernel8<<<2048, 256, 0, stream>>>(edst, cnt8);
        scan_block_sums<<<NB1, 256, 0, stream>>>(cnt8, bsum);
        scan_partials<<<1, 512, 0, stream>>>(bsum, boff);
        scan_write_offsets<<<NB1, 256, 0, stream>>>(cnt8, boff, node_off, cursor);
        reorder_xcd_kernel<<<2048, 256, 0, stream>>>(esrc, edst, ev, cursor, pairs);
        gather_reduce_kernel<<<(NN * 64 + 255) / 256, 256, 0, stream>>>(
            xb, node_off, pairs, eps, (uint2*)AXb);
        mlp_kernel<__bf16><<<nblk, 256, 0, stream>>>((const __bf16*)AXb, W1T, W2T, b1, b2, out);
    } else {
        // fallback: atomic scatter path (fp32 AX in d_out)
        __bf16* W1Tf = (__bf16*)ws;
        __bf16* W2Tf = W1Tf + 128 * 256;
        convert_kernel<<<128, 256, 0, stream>>>(W1, W2, W1Tf, W2Tf, (const float4*)x, (uint2*)nullptr);
        int n4 = NN * 128 / 4;
        init_ax_kernel<<<(n4 + 255) / 256, 256, 0, stream>>>((const float4*)x, (float4*)out, eps, n4);
        scatter_kernel<<<(NE * 64u) / 256u, 256, 0, stream>>>((const float2*)x, ev, esrc, edst, out);
        mlp_kernel<float><<<nblk, 256, 0, stream>>>(out, W1Tf, W2Tf, b1, b2, out);
    }
}